// Round 1
// baseline (4394.032 us; speedup 1.0000x reference)
//
#include <hip/hip_runtime.h>
#include <math.h>

#define NB 8
#define NC 64
#define NH 256
#define NW 256
#define NM 40      // 2*MODES1
#define NKX 20     // MODES2
#define NL 4

typedef _Float16 f16x8 __attribute__((ext_vector_type(8)));
typedef float    f32x4 __attribute__((ext_vector_type(4)));

// ---- workspace (floats) ----
#define PERCB_FLOATS ((size_t)(2*4194304 + 655360 + 2*102400))   // 9,248,768
#define FIXED_FLOATS ((size_t)(6553600 + 10240 + 20480 + 147456 + 256 + 167936 + 2048))

static __device__ __forceinline__ float gelu_f(float v) {
  return 0.5f * v * (1.f + erff(v * 0.70710678118654752f));
}
static __device__ __forceinline__ unsigned pack2(_Float16 a, _Float16 b) {
  union { _Float16 h[2]; unsigned u; } x; x.h[0] = a; x.h[1] = b; return x.u;
}

// ---------------------------------------------------------------------------
__global__ __launch_bounds__(256) void k_tables(float2* __restrict__ Tx,
                                                float2* __restrict__ Ty) {
  int t = blockIdx.x * 256 + threadIdx.x;
  const float w = (float)(2.0 * 3.14159265358979323846 / 256.0);
  if (t < NKX * 256) {
    int kx = t >> 8, x = t & 255;
    float th = (float)((kx * x) & 255) * w;
    Tx[t] = make_float2(cosf(th), sinf(th));
  }
  int u = t - NKX * 256;
  if (u >= 0 && u < NM * 256) {
    int m = u >> 8, y = u & 255;
    int ky = (m < 20) ? m : (m + 216);
    float th = (float)((ky * y) & 255) * w;
    Ty[u] = make_float2(cosf(th), sinf(th));
  }
}

// ---------------------------------------------------------------------------
// Pack forward-x twiddles into MFMA b-frag layout, split f16 hi/lo.
// B[k=x][n], n=2*kx+ri: re col = cos, im col = -sin. N padded 40->48.
// t = ((kc*3 + nt)*64 + lane)*8 + j
__global__ __launch_bounds__(256) void k_txpack(_Float16* __restrict__ th,
                                                _Float16* __restrict__ tl) {
  int t = blockIdx.x * 256 + threadIdx.x;   // 12288
  int j = t & 7, lane = (t >> 3) & 63;
  int rest = t >> 9;
  int nt = rest % 3, kc = rest / 3;
  int x = kc * 32 + ((lane >> 4) << 3) + j;
  int n = nt * 16 + (lane & 15);
  float val = 0.f;
  if (n < 40) {
    int kx = n >> 1;
    const float w = (float)(2.0 * 3.14159265358979323846 / 256.0);
    float ang = (float)((kx * x) & 255) * w;
    val = (n & 1) ? -sinf(ang) : cosf(ang);
  }
  _Float16 hi = (_Float16)val;
  th[t] = hi;
  tl[t] = (_Float16)(val - (float)hi);
}

// ---------------------------------------------------------------------------
__global__ __launch_bounds__(256) void k_wc(const float* __restrict__ ch,
                                            const float* __restrict__ cw,
                                            const float* __restrict__ pw,
                                            const float* __restrict__ chb,
                                            const float* __restrict__ cwb,
                                            const float* __restrict__ pwb,
                                            float* __restrict__ wc,
                                            float* __restrict__ bc) {
  int t = blockIdx.x * 256 + threadIdx.x;
  if (t < NL * NC * NC * 9) {
    int tap = t % 9;
    int io  = t / 9;
    int o   = io % 64;
    int i   = (io / 64) % 64;
    int l   = io / 4096;
    int src = ((l * 64 + o) * 64 + i) * 9 + tap;
    float v = ch[src] + cw[src];
    if (tap == 4) v += pw[(l * 64 + o) * 64 + i];
    wc[t] = v;
  }
  if (t < NL * NC) bc[t] = chb[t] + cwb[t] + pwb[t];
}

// ---------------------------------------------------------------------------
__global__ __launch_bounds__(256) void k_wpack(const float* __restrict__ wc,
                                               _Float16* __restrict__ whi,
                                               _Float16* __restrict__ wlo) {
  int t = blockIdx.x * 256 + threadIdx.x;     // 4*18*4*64 = 18432
  int lane = t & 63;
  int nt   = (t >> 6) & 3;
  int chunk = (t >> 8) % 18;
  int l4   = t / 4608;
  int tap = chunk >> 1, half = chunk & 1;
  int o = nt * 16 + (lane & 15);
  _Float16 hi[8], lo[8];
  #pragma unroll
  for (int j = 0; j < 8; ++j) {
    int i = half * 32 + ((lane >> 4) << 3) + j;
    float v = wc[((l4 * 64 + i) * 64 + o) * 9 + tap];
    _Float16 h = (_Float16)v;
    hi[j] = h;
    lo[j] = (_Float16)(v - (float)h);
  }
  *(f16x8*)(whi + (size_t)t * 8) = *(f16x8*)hi;
  *(f16x8*)(wlo + (size_t)t * 8) = *(f16x8*)lo;
}

// ---------------------------------------------------------------------------
__global__ __launch_bounds__(256) void k_hpack(const float* __restrict__ w1,
                                               _Float16* __restrict__ whi,
                                               _Float16* __restrict__ wlo) {
  int t = blockIdx.x * 256 + threadIdx.x;     // 2*8*64 = 1024
  int lane = t & 63;
  int nt   = (t >> 6) & 7;
  int chunk = t >> 9;
  int jo = nt * 16 + (lane & 15);
  _Float16 hi[8], lo[8];
  #pragma unroll
  for (int j = 0; j < 8; ++j) {
    int c = chunk * 32 + ((lane >> 4) << 3) + j;
    float v = w1[c * 128 + jo];
    _Float16 h = (_Float16)v;
    hi[j] = h;
    lo[j] = (_Float16)(v - (float)h);
  }
  *(f16x8*)(whi + (size_t)t * 8) = *(f16x8*)hi;
  *(f16x8*)(wlo + (size_t)t * 8) = *(f16x8*)lo;
}

// ---------------------------------------------------------------------------
// fc0 lift -> h in NHWC: h[px*64 + ch]
__global__ __launch_bounds__(256) void k_fc0(const float* __restrict__ x,
                                             const float* __restrict__ w,
                                             const float* __restrict__ b,
                                             float* __restrict__ h, int b0) {
  int t = blockIdx.x * 256 + threadIdx.x;    // cb*65536*64
  int ch = t & 63;
  int px = t >> 6;
  const float* xp = x + ((size_t)b0 * 65536 + px) * 3;
  h[t] = xp[0] * w[ch] + xp[1] * w[64 + ch] + xp[2] * w[128 + ch] + b[ch];
}

// ---------------------------------------------------------------------------
// Forward x-DFT as split-f16 MFMA GEMM. Block = (bb, y).
// C[c=64, n=48] = sum_x A[c,x] B[x,n];  A = h row (staged LDS, f16 hi/lo
// transposed to [ch][x]), B = prepacked twiddles. 2 K-stages of 128.
__global__ __launch_bounds__(256) void k_fwdx(const float* __restrict__ h,
                                              const f16x8* __restrict__ txh,
                                              const f16x8* __restrict__ txl,
                                              float2* __restrict__ Fx) {
  __shared__ _Float16 sH[64 * 136 * 2];    // hi [ch*136+xx], lo +8704
  int y = blockIdx.x & 255, bb = blockIdx.x >> 8;
  int tid = threadIdx.x;
  int w = tid >> 6, lane = tid & 63, quad = lane >> 4, l15 = lane & 15;
  const float* hp = h + ((size_t)(bb * 256 + y) * 256) * 64;

  f32x4 acc[3];
  #pragma unroll
  for (int nt = 0; nt < 3; ++nt) acc[nt] = (f32x4){0.f, 0.f, 0.f, 0.f};

  #pragma unroll 1
  for (int hs = 0; hs < 2; ++hs) {
    __syncthreads();
    #pragma unroll
    for (int it = 0; it < 8; ++it) {
      int e = it * 256 + tid;              // 2048
      int xx = e >> 4;                     // 0..127
      int chg = (e & 15) << 2;
      float4 v = *(const float4*)(hp + ((size_t)(hs * 128 + xx)) * 64 + chg);
      float vv[4] = {v.x, v.y, v.z, v.w};
      #pragma unroll
      for (int k = 0; k < 4; ++k) {
        _Float16 hi = (_Float16)vv[k];
        sH[(chg + k) * 136 + xx] = hi;
        sH[8704 + (chg + k) * 136 + xx] = (_Float16)(vv[k] - (float)hi);
      }
    }
    __syncthreads();
    #pragma unroll
    for (int kc = 0; kc < 4; ++kc) {
      int xb = kc * 32 + (quad << 3);
      f16x8 ah = *(const f16x8*)(sH + (w * 16 + l15) * 136 + xb);
      f16x8 al = *(const f16x8*)(sH + 8704 + (w * 16 + l15) * 136 + xb);
      int kcg = hs * 4 + kc;
      #pragma unroll
      for (int nt = 0; nt < 3; ++nt) {
        f16x8 bh = txh[(size_t)(kcg * 3 + nt) * 64 + lane];
        f16x8 bl = txl[(size_t)(kcg * 3 + nt) * 64 + lane];
        acc[nt] = __builtin_amdgcn_mfma_f32_16x16x32_f16(ah, bh, acc[nt], 0, 0, 0);
        acc[nt] = __builtin_amdgcn_mfma_f32_16x16x32_f16(ah, bl, acc[nt], 0, 0, 0);
        acc[nt] = __builtin_amdgcn_mfma_f32_16x16x32_f16(al, bh, acc[nt], 0, 0, 0);
      }
    }
  }
  // store: D row m = quad*4+r -> c = w*16+quad*4+r; col n = nt*16+l15
  #pragma unroll
  for (int nt = 0; nt < 3; ++nt) {
    int n = nt * 16 + l15;
    if (n < 40) {
      int kx = n >> 1, ri = n & 1;
      #pragma unroll
      for (int r = 0; r < 4; ++r) {
        int c = w * 16 + (quad << 2) + r;
        ((float*)(Fx + ((size_t)(bb * 64 + c) * 256 + y) * 20 + kx))[ri] = acc[nt][r];
      }
    }
  }
}

// ---------------------------------------------------------------------------
// Forward y-DFT. One block per bc; Fx slice (40 KB) in LDS, read once.
// Output transposed: FxyT[mk][bc].
__global__ __launch_bounds__(256) void k_fwdy(const float2* __restrict__ Fx,
                                              const float2* __restrict__ Ty,
                                              float2* __restrict__ FxyT, int nbc) {
  __shared__ float2 sFx[5120];
  int bc = blockIdx.x;
  const float4* src = (const float4*)(Fx + (size_t)bc * 5120);
  float4* dst = (float4*)sFx;
  for (int e = threadIdx.x; e < 2560; e += 256) dst[e] = src[e];
  __syncthreads();
  for (int mk = threadIdx.x; mk < 800; mk += 256) {
    int kx = mk % 20, m = mk / 20;
    const float2* tp = Ty + m * 256;
    float re = 0.f, im = 0.f;
    #pragma unroll 4
    for (int yy = 0; yy < 256; ++yy) {
      float2 f = sFx[yy * 20 + kx];
      float2 wv = tp[yy];
      re += f.x * wv.x + f.y * wv.y;
      im += f.y * wv.x - f.x * wv.y;
    }
    FxyT[(size_t)mk * nbc + bc] = make_float2(re * (1.f / 256.f), im * (1.f / 256.f));
  }
}

// ---------------------------------------------------------------------------
__global__ __launch_bounds__(256) void k_wT(const float* __restrict__ w1,
                                            const float* __restrict__ w2,
                                            float2* __restrict__ wT, int l) {
  __shared__ float2 tile[32][33];
  int mk0 = blockIdx.x * 32;   // 25
  int io0 = blockIdx.y * 32;   // 128
  int tx = threadIdx.x & 31, ty0 = threadIdx.x >> 5;
  #pragma unroll
  for (int s = 0; s < 4; ++s) {
    int ty = ty0 * 4 + s;
    int mk = mk0 + tx, io = io0 + ty;
    int m = mk / 20, kx = mk % 20;
    const float* src = (m < 20) ? w1 : w2;
    int mm = (m < 20) ? m : (m - 20);
    size_t idx = ((((size_t)l * 4096 + io) * 20 + mm) * 20 + kx) * 2;
    tile[ty][tx] = make_float2(src[idx], src[idx + 1]);
  }
  __syncthreads();
  #pragma unroll
  for (int s = 0; s < 4; ++s) {
    int ty = ty0 * 4 + s;
    wT[(size_t)(mk0 + ty) * 4096 + (io0 + tx)] = tile[tx][ty];
  }
}

// ---------------------------------------------------------------------------
__global__ __launch_bounds__(256) void k_mix(const float2* __restrict__ FxyT,
                                             const float2* __restrict__ wT,
                                             float2* __restrict__ G, int nrows) {
  __shared__ float2 sf[512];
  int mk = blockIdx.x;
  for (int t = threadIdx.x; t < nrows; t += 256)
    sf[t] = FxyT[(size_t)mk * nrows + t];
  __syncthreads();
  const float2* wp = wT + (size_t)mk * 4096;
  for (int t = threadIdx.x; t < nrows; t += 256) {
    int b = t >> 6, o = t & 63;
    const float2* fb = sf + b * 64;
    float re = 0.f, im = 0.f;
    #pragma unroll 8
    for (int i = 0; i < 64; ++i) {
      float2 f = fb[i];
      float2 w = wp[i * 64 + o];
      re += f.x * w.x - f.y * w.y;
      im += f.x * w.y + f.y * w.x;
    }
    G[(size_t)(b * 64 + o) * 800 + mk] = make_float2(re, im);
  }
}

// ---------------------------------------------------------------------------
__global__ __launch_bounds__(256) void k_invy(const float2* __restrict__ G,
                                              const float2* __restrict__ Ty,
                                              float2* __restrict__ Gy) {
  int t  = blockIdx.x * 256 + threadIdx.x;   // cb*64*256*20
  int kx = t % 20;
  int y  = (t / 20) & 255;
  int bc = t / 5120;
  const float2* gp = G + (size_t)bc * 800 + kx;
  float re = 0.f, im = 0.f;
  #pragma unroll 4
  for (int m = 0; m < 40; ++m) {
    float2 g = gp[m * 20];
    float2 w = Ty[m * 256 + y];
    re += g.x * w.x - g.y * w.y;
    im += g.x * w.y + g.y * w.x;
  }
  Gy[t] = make_float2(re, im);
}

// ---------------------------------------------------------------------------
// MFMA 3x3 conv + spectral add + gelu.
// Epilogue v4: results round-trip through LDS (sAu reused, 32 KB) so each
// wave emits 8x global_store_dwordx4 of 1 KB fully-contiguous data -- every
// 128 B output line fully dirtied by ONE instruction (kills partial-dirty-line
// eviction write amplification). XOR segment swizzle keeps LDS scatter/gather
// conflict-free.
// Grid decode v2: bb is the LOW bits of blockIdx -> (for cb=8) XCD = batch
// under round-robin assignment; the 8 xt-blocks sharing a Gy slice become
// consecutive blocks on one XCD, yt+-1 halo neighbors stay on-XCD.
__global__ __launch_bounds__(256, 3) void k_conv(const float* __restrict__ hin,
                                                 const f16x8* __restrict__ wph,
                                                 const f16x8* __restrict__ wpl,
                                                 const float* __restrict__ bcb,
                                                 const float2* __restrict__ Gy,
                                                 const float2* __restrict__ Tx,
                                                 float* __restrict__ hout,
                                                 int dogelu, int bsh) {
  __shared__ unsigned sAu[13056];            // 52224 B; reused in epilogue
  int bidx = blockIdx.x;
  int bb = bidx & ((1 << bsh) - 1);
  int rest = bidx >> bsh;
  int xt = rest & 7;
  int yt = (rest >> 3) & 63;
  int x0 = xt << 5, y0 = yt << 2;
  int tid = threadIdx.x;
  int w = tid >> 6, lane = tid & 63, quad = lane >> 4, l15 = lane & 15;

  float bias[4];
  #pragma unroll
  for (int nt = 0; nt < 4; ++nt) bias[nt] = bcb[nt * 16 + l15];

  // ---- stage activation tile (6x34 halo, 64 ch) as hi/lo f16, swizzled ----
  for (int e = tid; e < 204 * 32; e += 256) {
    int px = e >> 5, chp = e & 31;
    int rg = px / 34, cg = px % 34;
    int gy = y0 - 1 + rg, gx = x0 - 1 + cg;
    float2 v = make_float2(0.f, 0.f);
    if (gy >= 0 && gy < 256 && gx >= 0 && gx < 256)
      v = *(const float2*)(hin + (((size_t)bb * 256 + gy) * 256 + gx) * 64 + chp * 2);
    _Float16 h0 = (_Float16)v.x, h1 = (_Float16)v.y;
    _Float16 l0 = (_Float16)(v.x - (float)h0), l1 = (_Float16)(v.y - (float)h1);
    int dw = (px << 5) + (chp ^ ((px & 7) << 2));
    sAu[dw] = pack2(h0, h1);
    sAu[6528 + dw] = pack2(l0, l1);
  }
  __syncthreads();

  f32x4 acc[2][4];
  #pragma unroll
  for (int s = 0; s < 2; ++s)
    #pragma unroll
    for (int nt = 0; nt < 4; ++nt) acc[s][nt] = (f32x4){0.f, 0.f, 0.f, 0.f};

  // ---- main K loop ----
  #pragma unroll 1
  for (int tap = 0; tap < 9; ++tap) {
    int dy = tap / 3, dx = tap % 3;
    #pragma unroll
    for (int half = 0; half < 2; ++half) {
      int chunk = tap * 2 + half;
      const f16x8* bh = wph + (size_t)(chunk * 4) * 64 + lane;
      const f16x8* bl = wpl + (size_t)(chunk * 4) * 64 + lane;
      f16x8 bfh[4], bfl[4];
      #pragma unroll
      for (int nt = 0; nt < 4; ++nt) { bfh[nt] = bh[nt * 64]; bfl[nt] = bl[nt * 64]; }
      f16x8 afh[2], afl[2];
      #pragma unroll
      for (int s = 0; s < 2; ++s) {
        int px = (w + dy) * 34 + (s * 16 + dx) + l15;
        int dw = (px << 5) + (((half << 4) + (quad << 2)) ^ ((px & 7) << 2));
        afh[s] = *(const f16x8*)(sAu + dw);
        afl[s] = *(const f16x8*)(sAu + 6528 + dw);
      }
      #pragma unroll
      for (int s = 0; s < 2; ++s)
        #pragma unroll
        for (int nt = 0; nt < 4; ++nt) {
          acc[s][nt] = __builtin_amdgcn_mfma_f32_16x16x32_f16(afh[s], bfh[nt], acc[s][nt], 0, 0, 0);
          acc[s][nt] = __builtin_amdgcn_mfma_f32_16x16x32_f16(afh[s], bfl[nt], acc[s][nt], 0, 0, 0);
          acc[s][nt] = __builtin_amdgcn_mfma_f32_16x16x32_f16(afl[s], bfh[nt], acc[s][nt], 0, 0, 0);
        }
    }
  }

  // ---- epilogue ----
  __syncthreads();
  float2* sT  = (float2*)sAu;              // 640 f2  = 5120 B
  float2* sGy = (float2*)(sAu + 1280);     // 64*82 f2 = 41984 B; total 47104 B
  for (int e = tid; e < 640; e += 256) {
    int kx = e >> 5, col = e & 31;
    sT[e] = Tx[kx * 256 + x0 + col];
  }
  for (int e = tid; e < 5120; e += 256) {
    int o = e / 80, rem = e % 80;
    int row = rem / 20, kx = rem % 20;
    sGy[o * 82 + row * 20 + kx] =
        Gy[((size_t)(bb * 64 + o) * 256 + (y0 + row)) * 20 + kx];
  }
  __syncthreads();

  const float scale = 1.f / 256.f;
  #pragma unroll
  for (int s = 0; s < 2; ++s) {
    int colb = s * 16 + (quad << 2);
    #pragma unroll
    for (int nt = 0; nt < 4; ++nt) {
      int o = nt * 16 + l15;
      const float2* gp = sGy + o * 82 + w * 20;
      f32x4 sr = {0.f, 0.f, 0.f, 0.f};
      #pragma unroll
      for (int p = 0; p < 10; ++p) {
        float4 g = *(const float4*)(gp + 2 * p);
        float f0 = (p == 0) ? 1.f : 2.f;
        float4 tA = *(const float4*)(sT + (2 * p) * 32 + colb);
        float4 tB = *(const float4*)(sT + (2 * p) * 32 + colb + 2);
        sr.x += f0 * (g.x * tA.x - g.y * tA.y);
        sr.y += f0 * (g.x * tA.z - g.y * tA.w);
        sr.z += f0 * (g.x * tB.x - g.y * tB.y);
        sr.w += f0 * (g.x * tB.z - g.y * tB.w);
        float4 tC = *(const float4*)(sT + (2 * p + 1) * 32 + colb);
        float4 tD = *(const float4*)(sT + (2 * p + 1) * 32 + colb + 2);
        sr.x += 2.f * (g.z * tC.x - g.w * tC.y);
        sr.y += 2.f * (g.z * tC.z - g.w * tC.w);
        sr.z += 2.f * (g.z * tD.x - g.w * tD.y);
        sr.w += 2.f * (g.z * tD.z - g.w * tD.w);
      }
      #pragma unroll
      for (int r = 0; r < 4; ++r) {
        float v = acc[s][nt][r] + bias[nt] + sr[r] * scale;
        if (dogelu) v = gelu_f(v);
        acc[s][nt][r] = v;                 // finalize in place
      }
    }
  }

  // ---- LDS transpose: per-thread (pixel, ch-strided) -> per-lane float4 ----
  __syncthreads();
  float* sF = (float*)sAu;                 // 128 px * 64 ch = 32 KB
  #pragma unroll
  for (int s = 0; s < 2; ++s)
    #pragma unroll
    for (int nt = 0; nt < 4; ++nt)
      #pragma unroll
      for (int r = 0; r < 4; ++r) {
        int c = s * 16 + (quad << 2) + r;                 // pixel col 0..31
        int seg = nt ^ ((c >> 2) & 3);                    // 64B-segment swizzle
        sF[(w * 32 + c) * 64 + seg * 16 + l15] = acc[s][nt][r];
      }
  __syncthreads();

  // wave w owns output row y0+w: 8 KB contiguous, 8 x 1 KB dwordx4 stores
  float* op = hout + (((size_t)bb * 256 + (y0 + w)) * 256 + x0) * 64;
  #pragma unroll
  for (int i = 0; i < 8; ++i) {
    int chunk = i * 64 + lane;                            // 0..511
    int c = chunk >> 4, ch4 = chunk & 15;
    int seg = (ch4 >> 2) ^ ((c >> 2) & 3);
    float4 v = *(const float4*)(sF + (w * 32 + c) * 64 + seg * 16 + (ch4 & 3) * 4);
    *(float4*)(op + c * 64 + ch4 * 4) = v;
  }
}

// ---------------------------------------------------------------------------
// Head: MFMA fc1 (split-f16) + gelu + fc2 via shfl reduce. NHWC input.
__global__ __launch_bounds__(256, 2) void k_head(const float* __restrict__ h,
                                                 const f16x8* __restrict__ whi,
                                                 const f16x8* __restrict__ wlo,
                                                 const float* __restrict__ b1,
                                                 const float* __restrict__ w2,
                                                 const float* __restrict__ b2,
                                                 float* __restrict__ out, int b0) {
  int tid = threadIdx.x;
  int w = tid >> 6, lane = tid & 63, quad = lane >> 4, l15 = lane & 15;
  int px0 = blockIdx.x * 64 + w * 16;

  f32x4 acc[8];
  #pragma unroll
  for (int nt = 0; nt < 8; ++nt) acc[nt] = (f32x4){0.f, 0.f, 0.f, 0.f};

  #pragma unroll
  for (int half = 0; half < 2; ++half) {
    const float* ap = h + (size_t)(px0 + l15) * 64 + half * 32 + quad * 8;
    float4 a0 = *(const float4*)ap;
    float4 a1 = *(const float4*)(ap + 4);
    _Float16 ah[8], al[8];
    float av[8] = {a0.x, a0.y, a0.z, a0.w, a1.x, a1.y, a1.z, a1.w};
    #pragma unroll
    for (int j = 0; j < 8; ++j) {
      ah[j] = (_Float16)av[j];
      al[j] = (_Float16)(av[j] - (float)ah[j]);
    }
    f16x8 afh = *(f16x8*)ah, afl = *(f16x8*)al;
    #pragma unroll
    for (int nt = 0; nt < 8; ++nt) {
      f16x8 bh = whi[(size_t)(half * 8 + nt) * 64 + lane];
      f16x8 bl = wlo[(size_t)(half * 8 + nt) * 64 + lane];
      acc[nt] = __builtin_amdgcn_mfma_f32_16x16x32_f16(afh, bh, acc[nt], 0, 0, 0);
      acc[nt] = __builtin_amdgcn_mfma_f32_16x16x32_f16(afh, bl, acc[nt], 0, 0, 0);
      acc[nt] = __builtin_amdgcn_mfma_f32_16x16x32_f16(afl, bh, acc[nt], 0, 0, 0);
    }
  }

  float part[4] = {0.f, 0.f, 0.f, 0.f};
  #pragma unroll
  for (int nt = 0; nt < 8; ++nt) {
    int jo = nt * 16 + l15;
    float bb1 = b1[jo], ww2 = w2[jo];
    #pragma unroll
    for (int r = 0; r < 4; ++r)
      part[r] += gelu_f(acc[nt][r] + bb1) * ww2;
  }
  #pragma unroll
  for (int r = 0; r < 4; ++r) {
    float v = part[r];
    v += __shfl_xor(v, 1);
    v += __shfl_xor(v, 2);
    v += __shfl_xor(v, 4);
    v += __shfl_xor(v, 8);
    if (l15 == 0)
      out[(size_t)b0 * 65536 + px0 + quad * 4 + r] = v + b2[0];
  }
}

// ---------------------------------------------------------------------------
extern "C" void kernel_launch(void* const* d_in, const int* in_sizes, int n_in,
                              void* d_out, int out_size, void* d_ws, size_t ws_size,
                              hipStream_t stream) {
  const float* x    = (const float*)d_in[0];
  const float* fc0w = (const float*)d_in[1];
  const float* fc0b = (const float*)d_in[2];
  const float* w1   = (const float*)d_in[3];
  const float* w2   = (const float*)d_in[4];
  const float* chw  = (const float*)d_in[5];
  const float* chb  = (const float*)d_in[6];
  const float* cww  = (const float*)d_in[7];
  const float* cwb  = (const float*)d_in[8];
  const float* pww  = (const float*)d_in[9];
  const float* pwb  = (const float*)d_in[10];
  const float* fc1w = (const float*)d_in[11];
  const float* fc1b = (const float*)d_in[12];
  const float* fc2w = (const float*)d_in[13];
  const float* fc2b = (const float*)d_in[14];

  int cb = 1;
  for (int cand = 8; cand >= 1; cand >>= 1) {
    size_t need = (PERCB_FLOATS * (size_t)cand + FIXED_FLOATS) * sizeof(float);
    if (ws_size >= need) { cb = cand; break; }
  }
  int bsh = (cb == 8) ? 3 : (cb == 4) ? 2 : (cb == 2) ? 1 : 0;

  const size_t szH = (size_t)cb * 4194304;

  float*  ws  = (float*)d_ws;
  float*  h   = ws;
  float*  h2  = h + szH;
  float2* Fx  = (float2*)(h2 + szH);
  float2* Fxy = (float2*)((float*)Fx + (size_t)cb * 655360);
  float2* G   = (float2*)((float*)Fxy + (size_t)cb * 102400);
  float2* wT  = (float2*)((float*)G + (size_t)cb * 102400);
  float2* Tx  = (float2*)((float*)wT + 6553600);
  float2* Ty  = (float2*)((float*)Tx + 10240);
  float*  wcb = (float*)Ty + 20480;
  float*  bcb = wcb + 147456;
  _Float16* wpkhi = (_Float16*)(bcb + 256);
  _Float16* wpklo = wpkhi + 147456;
  _Float16* w1hi  = wpklo + 147456;
  _Float16* w1lo  = w1hi + 8192;
  _Float16* txph  = w1lo + 8192;
  _Float16* txpl  = txph + 12288;
  float2* Gy = Fx;   // Fx dead after k_fwdy

  k_tables<<<60, 256, 0, stream>>>(Tx, Ty);
  k_txpack<<<48, 256, 0, stream>>>(txph, txpl);
  k_wc<<<576, 256, 0, stream>>>(chw, cww, pww, chb, cwb, pwb, wcb, bcb);
  k_wpack<<<72, 256, 0, stream>>>(wcb, wpkhi, wpklo);
  k_hpack<<<4, 256, 0, stream>>>(fc1w, w1hi, w1lo);

  for (int b0 = 0; b0 < NB; b0 += cb) {
    k_fc0<<<cb * 16384, 256, 0, stream>>>(x, fc0w, fc0b, h, b0);
    float* cur = h;
    float* nxt = h2;
    int nbc = cb * 64;
    for (int l = 0; l < NL; ++l) {
      k_fwdx<<<cb * 256, 256, 0, stream>>>(cur, (const f16x8*)txph,
                                           (const f16x8*)txpl, Fx);
      k_fwdy<<<nbc, 256, 0, stream>>>(Fx, Ty, Fxy, nbc);
      k_wT<<<dim3(25, 128), 256, 0, stream>>>(w1, w2, wT, l);
      k_mix<<<NM * NKX, 256, 0, stream>>>(Fxy, wT, G, nbc);
      k_invy<<<cb * 1280, 256, 0, stream>>>(G, Ty, Gy);
      k_conv<<<cb * 512, 256, 0, stream>>>(cur,
                                           (const f16x8*)(wpkhi + (size_t)l * 36864),
                                           (const f16x8*)(wpklo + (size_t)l * 36864),
                                           bcb + (size_t)l * 64, Gy, Tx, nxt,
                                           (l < NL - 1) ? 1 : 0, bsh);
      float* tmp = cur; cur = nxt; nxt = tmp;
    }
    k_head<<<cb * 1024, 256, 0, stream>>>(cur, (const f16x8*)w1hi, (const f16x8*)w1lo,
                                          fc1b, fc2w, fc2b, (float*)d_out, b0);
  }
}